// Round 2
// baseline (2493.363 us; speedup 1.0000x reference)
//
#include <hip/hip_runtime.h>

#define NN 8192      // nodes
#define SS 20        // seq len
#define DD 256       // feat dim = H
#define RGATE 1024   // 4H
#define KKD 512      // D + H

typedef __attribute__((ext_vector_type(8))) short short8;
typedef __attribute__((ext_vector_type(4))) float f32x4;

__device__ __forceinline__ unsigned short f2bf(float f) {
    unsigned int u = __float_as_uint(f);
    u += 0x7FFFu + ((u >> 16) & 1u);   // round-to-nearest-even
    return (unsigned short)(u >> 16);
}

__device__ __forceinline__ void async_copy16(const void* g, void* l) {
    __builtin_amdgcn_global_load_lds(
        (const __attribute__((address_space(1))) void*)g,
        (__attribute__((address_space(3))) void*)l, 16, 0, 0);
}

__device__ __forceinline__ float sigm(float x) { return 1.0f / (1.0f + __expf(-x)); }
__device__ __forceinline__ float tanh_(float x) { return 2.0f / (1.0f + __expf(-2.0f * x)) - 1.0f; }

// ---------------------------------------------------------------------------
// Weight repack: Wcat[dir][r'][k], r' = 4*j + gate; k<256 -> w_ih, else w_hh.
// ---------------------------------------------------------------------------
__global__ void convert_w(const float* __restrict__ wihf, const float* __restrict__ whhf,
                          const float* __restrict__ bf,   const float* __restrict__ wihb,
                          const float* __restrict__ whhb, const float* __restrict__ bb,
                          unsigned short* __restrict__ Wcat, float* __restrict__ bperm) {
    const int idx = blockIdx.x * 256 + threadIdx.x;   // < 2*1024*512
    const int dir = idx >> 19;
    const int rem = idx & ((1 << 19) - 1);
    const int rp  = rem >> 9;          // r' in [0,1024)
    const int k   = rem & 511;
    const int j   = rp >> 2, gi = rp & 3;
    const int r   = gi * 256 + j;      // original row (PyTorch i,f,g,o blocks)
    const float* wih = dir ? wihb : wihf;
    const float* whh = dir ? whhb : whhf;
    const float v = (k < 256) ? wih[r * 256 + k] : whh[r * 256 + (k - 256)];
    Wcat[idx] = f2bf(v);
    if (k == 0) {
        const float* b = dir ? bb : bf;
        bperm[dir * 1024 + rp] = b[r];
    }
}

// ---------------------------------------------------------------------------
// Gather neighbor embeddings to bf16: X[t][n][256]. 4 waves/block, 1 row/wave.
// ---------------------------------------------------------------------------
__global__ __launch_bounds__(256) void gather_x(const float* __restrict__ emb,
                                                const int* __restrict__ idx,
                                                unsigned short* __restrict__ X) {
    const int w = threadIdx.x >> 6, lane = threadIdx.x & 63;
    #pragma unroll 4
    for (int i = 0; i < 16; ++i) {
        const int rid = (blockIdx.x * 16 + i) * 4 + w;   // 0..163839 = n*SS+t
        const int n = rid / SS, t = rid - n * SS;
        const int row = idx[rid];
        const float4 v = ((const float4*)(emb + (size_t)row * DD))[lane];
        ushort4 o;
        o.x = f2bf(v.x); o.y = f2bf(v.y); o.z = f2bf(v.z); o.w = f2bf(v.w);
        ((ushort4*)(X + ((size_t)t * NN + n) * DD))[lane] = o;
    }
}

// ---------------------------------------------------------------------------
// One LSTM step, both directions. Block tile 256x128 (M x R'), BK=64, 4 waves
// each owning 64 rows x 128 cols (acc[4][8]). XCD swizzle: blockIdx%8 = XCD;
// each XCD owns one dir + an 8-mblock slab + all 8 nblocks, so the A panel,
// W, and the h ping-pong stay in that XCD's L2 across all 20 steps.
// LDS staged via global_load_lds with a GLOBAL-side XOR-8 segment swizzle
// (seg' = seg ^ (row&7)) so fragment ds_read_b128s touch all 32 banks.
// ---------------------------------------------------------------------------
__global__ __launch_bounds__(256, 2) void lstm_step(
    const unsigned short* __restrict__ X,      // [SS][NN][256] bf16
    const unsigned short* __restrict__ Wcat,   // [2][1024][512] bf16
    const float* __restrict__ bperm,           // [2][1024]
    unsigned short* __restrict__ hping,        // [2 ping][2 dir][NN][256] bf16
    float* __restrict__ cstate,                // [2 dir][NN][256] f32
    float* __restrict__ hsum,                  // [NN] f32
    int s) {
    // ---- XCD-aware decode of a 1-D grid of 512 blocks ----
    const int b    = blockIdx.x;
    const int xcd  = b & 7;          // heuristic: dispatch round-robins XCDs
    const int slot = b >> 3;         // 0..63
    const int dir  = xcd & 1;
    const int xcdp = xcd >> 1;       // 0..3
    const int nblk = slot & 7;       // 0..7   (128 cols each)
    const int mblk = xcdp * 8 + (slot >> 3);   // 0..31 (256 rows each)

    const int t = dir ? (SS - 1 - s) : s;
    const unsigned short* Xt    = X + (size_t)t * NN * DD;
    const unsigned short* hprev = hping + ((size_t)((s & 1) * 2 + dir)) * NN * 256;
    unsigned short*       hnext = hping + ((size_t)((((s + 1) & 1) * 2) + dir)) * NN * 256;
    const unsigned short* W     = Wcat + (size_t)dir * RGATE * KKD;
    const float*          bp    = bperm + dir * RGATE;
    float*                cdir  = cstate + (size_t)dir * NN * 256;

    __shared__ char smem[49152];
    unsigned short* As = (unsigned short*)smem;            // 256 x 64 bf16 = 32 KB
    unsigned short* Bs = (unsigned short*)(smem + 32768);  // 128 x 64 bf16 = 16 KB

    const int tid  = threadIdx.x;
    const int lane = tid & 63;
    const int w    = tid >> 6;       // wave 0..3, owns rows w*64..w*64+63
    const int m0   = mblk * 256;
    const int n0   = nblk * 128;

    const int lrow = lane >> 3;                    // row within 8-row chunk
    const int gseg = (lane & 7) ^ lrow;            // XOR-swizzled global segment
    const int lcol = gseg * 8;                     // bf16 col of the 16B segment

    f32x4 acc[4][8];
    #pragma unroll
    for (int i = 0; i < 4; ++i)
        #pragma unroll
        for (int j = 0; j < 8; ++j)
            acc[i][j] = f32x4{0.f, 0.f, 0.f, 0.f};

    for (int kt = 0; kt < 8; ++kt) {
        const int k0 = kt * 64;
        const unsigned short* Abase = (kt < 4) ? (Xt + k0) : (hprev + (k0 - 256));
        // A: 32 chunks of 8 rows x 128 B
        #pragma unroll
        for (int q = 0; q < 8; ++q) {
            const int chunk = q * 4 + w;
            const int row   = chunk * 8 + lrow;    // 0..255
            async_copy16(Abase + (size_t)(m0 + row) * DD + lcol,
                         (void*)((char*)As + chunk * 1024));
        }
        // B: 16 chunks
        #pragma unroll
        for (int q = 0; q < 4; ++q) {
            const int chunk = q * 4 + w;
            const int row   = chunk * 8 + lrow;    // 0..127
            async_copy16(W + (size_t)(n0 + row) * KKD + k0 + lcol,
                         (void*)((char*)Bs + chunk * 1024));
        }
        __syncthreads();
        #pragma unroll
        for (int kk = 0; kk < 2; ++kk) {
            short8 af[4], bfr[8];
            const int quad = lane >> 4;
            const int lxor = lane & 7;
            #pragma unroll
            for (int mt = 0; mt < 4; ++mt) {
                const int r = w * 64 + mt * 16 + (lane & 15);
                const int segp = (kk * 4 + quad) ^ lxor;       // r&7 == lane&7
                af[mt] = *(const short8*)((const char*)As + r * 128 + segp * 16);
            }
            #pragma unroll
            for (int nt = 0; nt < 8; ++nt) {
                const int r = nt * 16 + (lane & 15);
                const int segp = (kk * 4 + quad) ^ lxor;
                bfr[nt] = *(const short8*)((const char*)Bs + r * 128 + segp * 16);
            }
            #pragma unroll
            for (int mt = 0; mt < 4; ++mt)
                #pragma unroll
                for (int nt = 0; nt < 8; ++nt)
                    acc[mt][nt] = __builtin_amdgcn_mfma_f32_16x16x32_bf16(
                        af[mt], bfr[nt], acc[mt][nt], 0, 0, 0);
        }
        __syncthreads();
    }

    // Epilogue: per 16-row slab, stage C through LDS (stride 132 breaks the
    // 16-way read conflict), regroup r'=4j+g quads, apply LSTM cell.
    float* eps   = (float*)smem;
    float* myeps = eps + w * 16 * 132;           // 8448 B per wave, 33792 total
    const int mloc_r = lane >> 2;                // 0..15
    const int jq     = lane & 3;                 // handles j_local jq*8..jq*8+7

    for (int mt = 0; mt < 4; ++mt) {
        #pragma unroll
        for (int nt = 0; nt < 8; ++nt) {
            #pragma unroll
            for (int v = 0; v < 4; ++v) {
                const int mloc = (lane >> 4) * 4 + v;        // C/D: row=quad*4+reg
                const int nloc = nt * 16 + (lane & 15);      //      col=lane&15
                myeps[mloc * 132 + nloc] = acc[mt][nt][v];
            }
        }
        __syncthreads();
        {
            const int mg = m0 + w * 64 + mt * 16 + mloc_r;   // node row
            float ssum = 0.f;
            #pragma unroll
            for (int hh = 0; hh < 2; ++hh) {
                const int jl0 = jq * 8 + hh * 4;             // j_local base
                const int jg0 = nblk * 32 + jl0;             // global hidden j
                const f32x4* brow = (const f32x4*)(bp + 4 * jg0);
                float* cptr = cdir + (size_t)mg * 256 + jg0;
                f32x4 cold = *(const f32x4*)cptr;
                f32x4 cnew;
                float hv[4];
                #pragma unroll
                for (int jj = 0; jj < 4; ++jj) {
                    f32x4 g  = *(const f32x4*)(myeps + mloc_r * 132 + 4 * (jl0 + jj));
                    f32x4 bb = brow[jj];
                    const float gi = sigm(g.x + bb.x);   // i
                    const float gf = sigm(g.y + bb.y);   // f
                    const float gg = tanh_(g.z + bb.z);  // g
                    const float go = sigm(g.w + bb.w);   // o
                    const float cn = gf * cold[jj] + gi * gg;
                    cnew[jj] = cn;
                    hv[jj] = go * tanh_(cn);
                }
                *(f32x4*)cptr = cnew;
                ushort4 hp;
                hp.x = f2bf(hv[0]); hp.y = f2bf(hv[1]); hp.z = f2bf(hv[2]); hp.w = f2bf(hv[3]);
                *(ushort4*)(hnext + (size_t)mg * 256 + jg0) = hp;
                ssum += hv[0] + hv[1] + hv[2] + hv[3];
            }
            ssum += __shfl_xor(ssum, 1);
            ssum += __shfl_xor(ssum, 2);
            if (jq == 0) atomicAdd(&hsum[mg], ssum);
        }
        __syncthreads();
    }
}

__global__ void bcast_out(const float* __restrict__ hsum, float* __restrict__ out) {
    const int n = blockIdx.x;
    const float v = hsum[n] * (1.0f / 512.0f);
    float2 p; p.x = v; p.y = v;
    ((float2*)(out + (size_t)n * 512))[threadIdx.x] = p;
}

extern "C" void kernel_launch(void* const* d_in, const int* in_sizes, int n_in,
                              void* d_out, int out_size, void* d_ws, size_t ws_size,
                              hipStream_t stream) {
    const float* emb  = (const float*)d_in[0];
    const float* wihf = (const float*)d_in[1];
    const float* whhf = (const float*)d_in[2];
    const float* bf   = (const float*)d_in[3];
    const float* wihb = (const float*)d_in[4];
    const float* whhb = (const float*)d_in[5];
    const float* bb   = (const float*)d_in[6];
    const int*   idx  = (const int*)d_in[7];
    float* out = (float*)d_out;

    // workspace layout (bytes)
    char* ws = (char*)d_ws;
    unsigned short* X     = (unsigned short*)(ws);               // 83,886,080  X[t][n][256] bf16
    unsigned short* Wcat  = (unsigned short*)(ws + 83886080);    //  2,097,152  [2][1024][512] bf16
    float*          bperm = (float*)(ws + 85983232);             //      8,192  [2][1024] f32
    unsigned short* hping = (unsigned short*)(ws + 85991424);    // 16,777,216  [2][2][8192][256] bf16
    float*          cst   = (float*)(ws + 102768640);            // 16,777,216  [2][8192][256] f32
    float*          hsum  = (float*)(ws + 119545856);            //     32,768  [8192] f32
    // total: 119,578,624 B

    hipMemsetAsync(hping, 0, 8388608, stream);                   // h ping0, both dirs
    hipMemsetAsync(cst, 0, 16777216 + 32768, stream);            // c + hsum (contiguous)

    convert_w<<<4096, 256, 0, stream>>>(wihf, whhf, bf, wihb, whhb, bb, Wcat, bperm);
    gather_x<<<2560, 256, 0, stream>>>(emb, idx, X);
    for (int s = 0; s < SS; ++s)
        lstm_step<<<512, 256, 0, stream>>>(X, Wcat, bperm, hping, cst, hsum, s);
    bcast_out<<<NN, 256, 0, stream>>>(hsum, out);
}

// Round 3
// 917.898 us; speedup vs baseline: 2.7164x; 2.7164x over previous
//
#include <hip/hip_runtime.h>

#define NN 8192      // nodes
#define SS 20        // seq len
#define DD 256       // feat dim = H
#define RGATE 1024   // 4H
#define KKD 512      // D + H

typedef __attribute__((ext_vector_type(8))) short short8;
typedef __attribute__((ext_vector_type(4))) float f32x4;

__device__ __forceinline__ unsigned short f2bf(float f) {
    unsigned int u = __float_as_uint(f);
    u += 0x7FFFu + ((u >> 16) & 1u);   // round-to-nearest-even
    return (unsigned short)(u >> 16);
}

__device__ __forceinline__ void async_copy16(const void* g, void* l) {
    __builtin_amdgcn_global_load_lds(
        (const __attribute__((address_space(1))) void*)g,
        (__attribute__((address_space(3))) void*)l, 16, 0, 0);
}

__device__ __forceinline__ float sigm(float x) { return 1.0f / (1.0f + __expf(-x)); }
__device__ __forceinline__ float tanh_(float x) { return 2.0f / (1.0f + __expf(-2.0f * x)) - 1.0f; }

// ---------------------------------------------------------------------------
// Weight repack: Wcat[dir][r'][k], r' = 4*j + gate; k<256 -> w_ih, else w_hh.
// ---------------------------------------------------------------------------
__global__ void convert_w(const float* __restrict__ wihf, const float* __restrict__ whhf,
                          const float* __restrict__ bf,   const float* __restrict__ wihb,
                          const float* __restrict__ whhb, const float* __restrict__ bb,
                          unsigned short* __restrict__ Wcat, float* __restrict__ bperm) {
    const int idx = blockIdx.x * 256 + threadIdx.x;   // < 2*1024*512
    const int dir = idx >> 19;
    const int rem = idx & ((1 << 19) - 1);
    const int rp  = rem >> 9;          // r' in [0,1024)
    const int k   = rem & 511;
    const int j   = rp >> 2, gi = rp & 3;
    const int r   = gi * 256 + j;      // original row (PyTorch i,f,g,o blocks)
    const float* wih = dir ? wihb : wihf;
    const float* whh = dir ? whhb : whhf;
    const float v = (k < 256) ? wih[r * 256 + k] : whh[r * 256 + (k - 256)];
    Wcat[idx] = f2bf(v);
    if (k == 0) {
        const float* b = dir ? bb : bf;
        bperm[dir * 1024 + rp] = b[r];
    }
}

// ---------------------------------------------------------------------------
// Gather neighbor embeddings to bf16: X[t][n][256]. 4 waves/block, 1 row/wave.
// ---------------------------------------------------------------------------
__global__ __launch_bounds__(256) void gather_x(const float* __restrict__ emb,
                                                const int* __restrict__ idx,
                                                unsigned short* __restrict__ X) {
    const int w = threadIdx.x >> 6, lane = threadIdx.x & 63;
    #pragma unroll 4
    for (int i = 0; i < 16; ++i) {
        const int rid = (blockIdx.x * 16 + i) * 4 + w;   // 0..163839 = n*SS+t
        const int n = rid / SS, t = rid - n * SS;
        const int row = idx[rid];
        const float4 v = ((const float4*)(emb + (size_t)row * DD))[lane];
        ushort4 o;
        o.x = f2bf(v.x); o.y = f2bf(v.y); o.z = f2bf(v.z); o.w = f2bf(v.w);
        ((ushort4*)(X + ((size_t)t * NN + n) * DD))[lane] = o;
    }
}

// ---------------------------------------------------------------------------
// One LSTM step, both directions. Block tile 128x128 (M x R'), BK=64, 4 waves
// in a 2x2 layout, acc[4][4] (64 acc VGPRs -> NO SPILL; R2's acc[4][8]=128
// spilled and cost 524 MB/step of scratch writebacks).
// XCD decode (b&7 = XCD, assuming round-robin dispatch): each XCD owns one
// dir + a 16-mblk slab x all 8 nblks, so W (1 MB), c-slab (2 MB), h-slabs
// (1 MB) stay in that XCD's 4 MB L2 across steps; A panels get 8-way reuse
// from co-resident nblk-sharers.
// Global-side XOR-8 segment swizzle: LDS word16 slot (lane&7) of row r holds
// global segment (lane&7)^(r&7); fragment reads use segp=(seg)^(r&7) so each
// ds_read_b128 touches all 32 banks (structural 8-cycle floor, was 2x).
// ---------------------------------------------------------------------------
__global__ __launch_bounds__(256) void lstm_step(
    const unsigned short* __restrict__ X,      // [SS][NN][256] bf16
    const unsigned short* __restrict__ Wcat,   // [2][1024][512] bf16
    const float* __restrict__ bperm,           // [2][1024]
    unsigned short* __restrict__ hping,        // [2 ping][2 dir][NN][256] bf16
    float* __restrict__ cstate,                // [2 dir][NN][256] f32
    float* __restrict__ hsum,                  // [NN] f32
    int s) {
    // ---- XCD-aware decode of a 1-D grid of 1024 blocks ----
    const int b    = blockIdx.x;
    const int xcd  = b & 7;                    // round-robin heuristic
    const int slot = b >> 3;                   // 0..127
    const int dir  = xcd & 1;
    const int xcdp = xcd >> 1;                 // 0..3
    const int nblk = slot & 7;                 // 0..7   (128 gate-cols each)
    const int mblk = xcdp * 16 + (slot >> 3);  // 0..63  (128 rows each)

    const int t = dir ? (SS - 1 - s) : s;
    const unsigned short* Xt    = X + (size_t)t * NN * DD;
    const unsigned short* hprev = hping + ((size_t)((s & 1) * 2 + dir)) * NN * 256;
    unsigned short*       hnext = hping + ((size_t)((((s + 1) & 1) * 2) + dir)) * NN * 256;
    const unsigned short* W     = Wcat + (size_t)dir * RGATE * KKD;
    const float*          bp    = bperm + dir * RGATE;
    float*                cdir  = cstate + (size_t)dir * NN * 256;

    __shared__ char smem[34816];               // 34 KB -> 4 blocks/CU
    unsigned short* As = (unsigned short*)smem;            // 128 x 64 bf16 = 16 KB
    unsigned short* Bs = (unsigned short*)(smem + 16384);  // 128 x 64 bf16 = 16 KB

    const int tid  = threadIdx.x;
    const int lane = tid & 63;
    const int w    = tid >> 6;       // wave 0..3
    const int wm   = w >> 1, wn = w & 1;
    const int m0   = mblk * 128;
    const int n0   = nblk * 128;

    const int lrow = lane >> 3;                    // row within 8-row chunk
    const int gseg = (lane & 7) ^ lrow;            // XOR-swizzled global segment
    const int lcol = gseg * 8;                     // bf16 col of the 16B segment

    f32x4 acc[4][4];
    #pragma unroll
    for (int i = 0; i < 4; ++i)
        #pragma unroll
        for (int j = 0; j < 4; ++j)
            acc[i][j] = f32x4{0.f, 0.f, 0.f, 0.f};

    for (int kt = 0; kt < 8; ++kt) {
        const int k0 = kt * 64;
        const unsigned short* Abase = (kt < 4) ? (Xt + k0) : (hprev + (k0 - 256));
        #pragma unroll
        for (int q = 0; q < 4; ++q) {
            const int chunk = q * 4 + w;          // wave-uniform LDS chunk (1024 B)
            const int row   = chunk * 8 + lrow;   // 0..127
            async_copy16(Abase + (size_t)(m0 + row) * DD + lcol,
                         (void*)((char*)As + chunk * 1024));
            async_copy16(W + (size_t)(n0 + row) * KKD + k0 + lcol,
                         (void*)((char*)Bs + chunk * 1024));
        }
        __syncthreads();
        #pragma unroll
        for (int kk = 0; kk < 2; ++kk) {
            short8 af[4], bfr[4];
            const int quad = lane >> 4;
            const int lxor = lane & 7;
            const int segp = ((kk * 4 + quad) ^ lxor) * 16;  // byte offset of segment
            #pragma unroll
            for (int mt = 0; mt < 4; ++mt) {
                const int r = wm * 64 + mt * 16 + (lane & 15);   // r&7 == lane&7
                af[mt] = *(const short8*)((const char*)As + r * 128 + segp);
            }
            #pragma unroll
            for (int nt = 0; nt < 4; ++nt) {
                const int r = wn * 64 + nt * 16 + (lane & 15);
                bfr[nt] = *(const short8*)((const char*)Bs + r * 128 + segp);
            }
            #pragma unroll
            for (int mt = 0; mt < 4; ++mt)
                #pragma unroll
                for (int nt = 0; nt < 4; ++nt)
                    acc[mt][nt] = __builtin_amdgcn_mfma_f32_16x16x32_bf16(
                        af[mt], bfr[nt], acc[mt][nt], 0, 0, 0);
        }
        __syncthreads();
    }

    // Epilogue: per 16-row slab, stage C through LDS with stride 68 floats
    // (breaks the stride-64 64-way read conflict), regroup r'=4j+g quads,
    // apply LSTM cell.
    float* eps   = (float*)smem;                 // 4 waves x 16 x 68 floats = 17408 B
    float* myeps = eps + w * 16 * 68;
    const int mloc_r = lane >> 2;                // 0..15
    const int jq     = lane & 3;                 // group of 4 hidden units

    for (int mt = 0; mt < 4; ++mt) {
        #pragma unroll
        for (int nt = 0; nt < 4; ++nt) {
            #pragma unroll
            for (int v = 0; v < 4; ++v) {
                const int mloc = (lane >> 4) * 4 + v;        // C/D: row=quad*4+reg
                const int nloc = nt * 16 + (lane & 15);      //      col=lane&15
                myeps[mloc * 68 + nloc] = acc[mt][nt][v];
            }
        }
        __syncthreads();
        {
            const int mg  = m0 + wm * 64 + mt * 16 + mloc_r;            // node row
            const int jg0 = nblk * 32 + wn * 16 + jq * 4;               // first hidden j
            const f32x4* brow = (const f32x4*)(bp + 4 * jg0);
            float* cptr = cdir + (size_t)mg * 256 + jg0;
            f32x4 cold = *(const f32x4*)cptr;
            f32x4 cnew;
            float hv[4];
            #pragma unroll
            for (int jj = 0; jj < 4; ++jj) {
                f32x4 g  = *(const f32x4*)(myeps + mloc_r * 68 + jq * 16 + jj * 4);
                f32x4 bb = brow[jj];
                const float gi = sigm(g.x + bb.x);   // i
                const float gf = sigm(g.y + bb.y);   // f
                const float gg = tanh_(g.z + bb.z);  // g
                const float go = sigm(g.w + bb.w);   // o
                const float cn = gf * cold[jj] + gi * gg;
                cnew[jj] = cn;
                hv[jj] = go * tanh_(cn);
            }
            *(f32x4*)cptr = cnew;
            ushort4 hp;
            hp.x = f2bf(hv[0]); hp.y = f2bf(hv[1]); hp.z = f2bf(hv[2]); hp.w = f2bf(hv[3]);
            *(ushort4*)(hnext + (size_t)mg * 256 + jg0) = hp;
            float ssum = hv[0] + hv[1] + hv[2] + hv[3];
            ssum += __shfl_xor(ssum, 1);
            ssum += __shfl_xor(ssum, 2);
            if (jq == 0) atomicAdd(&hsum[mg], ssum);
        }
        __syncthreads();
    }
}

__global__ void bcast_out(const float* __restrict__ hsum, float* __restrict__ out) {
    const int n = blockIdx.x;
    const float v = hsum[n] * (1.0f / 512.0f);
    float2 p; p.x = v; p.y = v;
    ((float2*)(out + (size_t)n * 512))[threadIdx.x] = p;
}

extern "C" void kernel_launch(void* const* d_in, const int* in_sizes, int n_in,
                              void* d_out, int out_size, void* d_ws, size_t ws_size,
                              hipStream_t stream) {
    const float* emb  = (const float*)d_in[0];
    const float* wihf = (const float*)d_in[1];
    const float* whhf = (const float*)d_in[2];
    const float* bf   = (const float*)d_in[3];
    const float* wihb = (const float*)d_in[4];
    const float* whhb = (const float*)d_in[5];
    const float* bb   = (const float*)d_in[6];
    const int*   idx  = (const int*)d_in[7];
    float* out = (float*)d_out;

    // workspace layout (bytes)
    char* ws = (char*)d_ws;
    unsigned short* X     = (unsigned short*)(ws);               // 83,886,080  X[t][n][256] bf16
    unsigned short* Wcat  = (unsigned short*)(ws + 83886080);    //  2,097,152  [2][1024][512] bf16
    float*          bperm = (float*)(ws + 85983232);             //      8,192  [2][1024] f32
    unsigned short* hping = (unsigned short*)(ws + 85991424);    // 16,777,216  [2][2][8192][256] bf16
    float*          cst   = (float*)(ws + 102768640);            // 16,777,216  [2][8192][256] f32
    float*          hsum  = (float*)(ws + 119545856);            //     32,768  [8192] f32
    // total: 119,578,624 B

    hipMemsetAsync(hping, 0, 8388608, stream);                   // h ping0, both dirs
    hipMemsetAsync(cst, 0, 16777216 + 32768, stream);            // c + hsum (contiguous)

    convert_w<<<4096, 256, 0, stream>>>(wihf, whhf, bf, wihb, whhb, bb, Wcat, bperm);
    gather_x<<<2560, 256, 0, stream>>>(emb, idx, X);
    for (int s = 0; s < SS; ++s)
        lstm_step<<<1024, 256, 0, stream>>>(X, Wcat, bperm, hping, cst, hsum, s);
    bcast_out<<<NN, 256, 0, stream>>>(hsum, out);
}